// Round 4
// baseline (277.332 us; speedup 1.0000x reference)
//
#include <hip/hip_runtime.h>
#include <hip/hip_bf16.h>

// ---------------------------------------------------------------------------
// B=2, S=2048, D=768, H=12, Dh=64. M = B*S = 4096.
// Full bf16-MFMA pipeline: cast/transpose prep -> 3 QKV GEMMs -> flash attn
// -> output GEMM. All matmuls on v_mfma_f32_16x16x32_bf16, fp32 accumulate.
// ---------------------------------------------------------------------------

typedef __attribute__((ext_vector_type(8))) short short8;   // 8 x bf16 (4 VGPR)
typedef __attribute__((ext_vector_type(4))) float float4e;  // 4 x fp32 acc

// round-to-nearest-even fp32 -> bf16
__device__ __forceinline__ ushort f2bf(float f) {
    union { float f; unsigned u; } v; v.f = f;
    unsigned r = v.u + 0x7FFF + ((v.u >> 16) & 1);
    return (ushort)(r >> 16);
}

// ===========================================================================
// x [4096x768] fp32 -> bf16 (vectorized 4/thread)
// ===========================================================================
__global__ __launch_bounds__(256) void cast_f32_bf16(
    const float* __restrict__ in, ushort* __restrict__ out, int n4)
{
    int i = blockIdx.x * blockDim.x + threadIdx.x;
    if (i < n4) {
        float4 v = *(const float4*)&in[(size_t)i * 4];
        ushort4 o;
        o.x = f2bf(v.x); o.y = f2bf(v.y); o.z = f2bf(v.z); o.w = f2bf(v.w);
        *(ushort4*)&out[(size_t)i * 4] = o;
    }
}

// ===========================================================================
// W [768x768] fp32 (k-major) -> Wt [768x768] bf16 with Wt[n][k] = W[k][n].
// 64x64 LDS tile, +1 pad -> conflict-free transposed reads.
// ===========================================================================
__global__ __launch_bounds__(256) void transpose_cast_w(
    const float* __restrict__ W, ushort* __restrict__ Wt)
{
    __shared__ float t[64][65];
    const int tid = threadIdx.x;
    const int c  = tid & 63;
    const int rg = tid >> 6;
    const int k0 = blockIdx.y * 64, n0 = blockIdx.x * 64;
    #pragma unroll
    for (int r = 0; r < 16; ++r) {
        const int row = rg * 16 + r;
        t[row][c] = W[(size_t)(k0 + row) * 768 + n0 + c];
    }
    __syncthreads();
    #pragma unroll
    for (int r = 0; r < 16; ++r) {
        const int row = rg * 16 + r;
        Wt[(size_t)(n0 + row) * 768 + k0 + c] = f2bf(t[c][row]);
    }
}

// ===========================================================================
// GEMM: C[M,N] = A[M,K](bf16) @ Bt[N,K](bf16)^T + bias(fp32)
// 64x64 tile, BK=32, 4 waves; wave w = rows [16w,16w+16) x 64 cols (4 accs).
// LDS rows padded to 40 shorts (80B): 16B-aligned b128 frags, 2-way bank
// alias only (free). C/D layout: col=lane&15, row=quad*4+reg (measured).
// Staging: 64 rows x 32 ushorts = 256 thr x 8 ushorts (one uint4 each).
// ===========================================================================
template <bool OUT_BF16>
__global__ __launch_bounds__(256) void gemm_bt_bias(
    const ushort* __restrict__ A, const ushort* __restrict__ Bt,
    const float* __restrict__ bias, void* __restrict__ Cout,
    int M, int N, int K)
{
    __shared__ ushort As[64][40];
    __shared__ ushort Bs[64][40];

    const int tid  = threadIdx.x;
    const int w    = tid >> 6;
    const int lane = tid & 63;
    const int l16  = lane & 15;
    const int quad = lane >> 4;
    const int row0 = blockIdx.y * 64, col0 = blockIdx.x * 64;
    const int sr = tid >> 2, sc = (tid & 3) * 8;   // staging: 16B per thread

    float4e acc[4];
    #pragma unroll
    for (int n = 0; n < 4; ++n) acc[n] = (float4e){0.f, 0.f, 0.f, 0.f};

    for (int k0 = 0; k0 < K; k0 += 32) {
        *(uint4*)&As[sr][sc] = *(const uint4*)&A [(size_t)(row0 + sr) * K + k0 + sc];
        *(uint4*)&Bs[sr][sc] = *(const uint4*)&Bt[(size_t)(col0 + sr) * K + k0 + sc];
        __syncthreads();

        const short8 a = *(const short8*)&As[w * 16 + l16][quad * 8];
        #pragma unroll
        for (int n = 0; n < 4; ++n) {
            const short8 b = *(const short8*)&Bs[n * 16 + l16][quad * 8];
            acc[n] = __builtin_amdgcn_mfma_f32_16x16x32_bf16(a, b, acc[n], 0, 0, 0);
        }
        __syncthreads();
    }

    #pragma unroll
    for (int n = 0; n < 4; ++n) {
        const int col = col0 + n * 16 + l16;
        const float bs = bias[col];
        #pragma unroll
        for (int r = 0; r < 4; ++r) {
            const int row = row0 + w * 16 + quad * 4 + r;
            const float vv = acc[n][r] + bs;
            if (OUT_BF16) ((ushort*)Cout)[(size_t)row * N + col] = f2bf(vv);
            else          ((float*) Cout)[(size_t)row * N + col] = vv;
        }
    }
}

// ===========================================================================
// Flash attention, bf16 MFMA, NO 1/sqrt(dh) scale (matches reference).
// Block = (b, h, 64 queries); wave w owns queries [16w,16w+16).
// Q frags in registers; K staged [key][d]; V staged transposed [d][key];
// P round-trips through LDS (C-layout -> A-layout), wave-private rows.
// Online softmax fp32: row = quad*4+r, reduce over 16 lanes (xor 1,2,4,8).
//
// FIX (round 3): K/V tiles are 64 rows x 64 ushorts (Dh=64) = 8192 B each;
// staging is now sr=tid>>2, sc=(tid&3)*16, TWO uint4 loads per thread
// (prev version staged only cols 0..31 -> cols 32..63 were uninitialized
// LDS -> NaN scores).
// ===========================================================================
__global__ __launch_bounds__(256) void attn_mfma(
    const ushort* __restrict__ Qg, const ushort* __restrict__ Kgl,
    const ushort* __restrict__ Vg, ushort* __restrict__ Ctx)
{
    constexpr int S = 2048, D = 768;
    __shared__ ushort Ks [64][72];   // rows 144B: 16B-aligned, 2-way alias only
    __shared__ ushort Vts[64][72];
    __shared__ ushort Ps [64][72];

    const int tid  = threadIdx.x;
    const int w    = tid >> 6;
    const int lane = tid & 63;
    const int l16  = lane & 15;
    const int quad = lane >> 4;
    const int b = blockIdx.z, h = blockIdx.y, q0 = blockIdx.x * 64;
    const size_t hc = (size_t)h * 64;

    // Q fragments for this wave's 16 query rows (held all kernel)
    const size_t qoff = (size_t)(b * S + q0 + w * 16 + l16) * D + hc + quad * 8;
    const short8 aq0 = *(const short8*)&Qg[qoff];
    const short8 aq1 = *(const short8*)&Qg[qoff + 32];

    float mrow[4], lrow[4];
    float4e oa[4];
    #pragma unroll
    for (int r = 0; r < 4; ++r) { mrow[r] = -1e30f; lrow[r] = 0.f; }
    #pragma unroll
    for (int n = 0; n < 4; ++n) oa[n] = (float4e){0.f, 0.f, 0.f, 0.f};

    const int sr = tid >> 2;          // 0..63: K/V row
    const int sc = (tid & 3) * 16;    // 0,16,32,48: col start (ushorts)

    for (int k0 = 0; k0 < S; k0 += 64) {
        // ---- stage K tile and transposed V tile (full 64 cols!) ----
        const size_t gk = (size_t)(b * S + k0 + sr) * D + hc + sc;
        *(uint4*)&Ks[sr][sc    ] = *(const uint4*)&Kgl[gk];
        *(uint4*)&Ks[sr][sc + 8] = *(const uint4*)&Kgl[gk + 8];
        uint4 va4 = *(const uint4*)&Vg[gk];
        uint4 vb4 = *(const uint4*)&Vg[gk + 8];
        const ushort* vu = (const ushort*)&va4;
        const ushort* vu2 = (const ushort*)&vb4;
        #pragma unroll
        for (int i = 0; i < 8; ++i) Vts[sc + i][sr] = vu[i];
        #pragma unroll
        for (int i = 0; i < 8; ++i) Vts[sc + 8 + i][sr] = vu2[i];
        __syncthreads();

        // ---- scores: S = Q K^T (chain 2 MFMAs over d) ----
        float4e sa[4];
        #pragma unroll
        for (int n = 0; n < 4; ++n) {
            const short8 b0 = *(const short8*)&Ks[n * 16 + l16][quad * 8];
            const short8 b1 = *(const short8*)&Ks[n * 16 + l16][32 + quad * 8];
            float4e z = (float4e){0.f, 0.f, 0.f, 0.f};
            z     = __builtin_amdgcn_mfma_f32_16x16x32_bf16(aq0, b0, z, 0, 0, 0);
            sa[n] = __builtin_amdgcn_mfma_f32_16x16x32_bf16(aq1, b1, z, 0, 0, 0);
        }

        // ---- online softmax (fp32), P -> LDS as bf16 ----
        #pragma unroll
        for (int r = 0; r < 4; ++r) {
            float mx = fmaxf(fmaxf(sa[0][r], sa[1][r]), fmaxf(sa[2][r], sa[3][r]));
            #pragma unroll
            for (int off = 1; off < 16; off <<= 1)
                mx = fmaxf(mx, __shfl_xor(mx, off, 64));
            const float mn = fmaxf(mrow[r], mx);
            const float alpha = __expf(mrow[r] - mn);   // first iter: 0
            const float p0 = __expf(sa[0][r] - mn);
            const float p1 = __expf(sa[1][r] - mn);
            const float p2 = __expf(sa[2][r] - mn);
            const float p3 = __expf(sa[3][r] - mn);
            float ps = p0 + p1 + p2 + p3;
            #pragma unroll
            for (int off = 1; off < 16; off <<= 1)
                ps += __shfl_xor(ps, off, 64);
            lrow[r] = lrow[r] * alpha + ps;
            mrow[r] = mn;
            const int prow = w * 16 + quad * 4 + r;
            Ps[prow][ 0 + l16] = f2bf(p0);
            Ps[prow][16 + l16] = f2bf(p1);
            Ps[prow][32 + l16] = f2bf(p2);
            Ps[prow][48 + l16] = f2bf(p3);
            oa[0][r] *= alpha; oa[1][r] *= alpha;
            oa[2][r] *= alpha; oa[3][r] *= alpha;
        }

        // ---- PV: O += P V  (Ps rows are wave-private; in-wave DS order ok) ----
        const short8 ap0 = *(const short8*)&Ps[w * 16 + l16][quad * 8];
        const short8 ap1 = *(const short8*)&Ps[w * 16 + l16][32 + quad * 8];
        #pragma unroll
        for (int n = 0; n < 4; ++n) {
            const short8 bv0 = *(const short8*)&Vts[n * 16 + l16][quad * 8];
            const short8 bv1 = *(const short8*)&Vts[n * 16 + l16][32 + quad * 8];
            oa[n] = __builtin_amdgcn_mfma_f32_16x16x32_bf16(ap0, bv0, oa[n], 0, 0, 0);
            oa[n] = __builtin_amdgcn_mfma_f32_16x16x32_bf16(ap1, bv1, oa[n], 0, 0, 0);
        }
        __syncthreads();   // protect Ks/Vts before next staging
    }

    // ---- normalize and write ctx (bf16) ----
    #pragma unroll
    for (int n = 0; n < 4; ++n) {
        #pragma unroll
        for (int r = 0; r < 4; ++r) {
            const int row = b * S + q0 + w * 16 + quad * 4 + r;
            Ctx[(size_t)row * D + hc + n * 16 + l16] = f2bf(oa[n][r] / lrow[r]);
        }
    }
}

// ===========================================================================
// Launch
// ===========================================================================
extern "C" void kernel_launch(void* const* d_in, const int* in_sizes, int n_in,
                              void* d_out, int out_size, void* d_ws, size_t ws_size,
                              hipStream_t stream)
{
    const float* x  = (const float*)d_in[0];
    const float* Wq = (const float*)d_in[1];
    const float* bq = (const float*)d_in[2];
    const float* Wk = (const float*)d_in[3];
    const float* bk = (const float*)d_in[4];
    const float* Wv = (const float*)d_in[5];
    const float* bv = (const float*)d_in[6];
    const float* Wo = (const float*)d_in[7];
    const float* bo = (const float*)d_in[8];

    const int M = 4096, D = 768;
    const size_t XE = (size_t)M * D;     // 3,145,728
    const size_t WE = (size_t)D * D;     //   589,824

    ushort* xb   = (ushort*)d_ws;        // total ws use: ~36.2 MB
    ushort* wtq  = xb   + XE;
    ushort* wtk  = wtq  + WE;
    ushort* wtv  = wtk  + WE;
    ushort* wto  = wtv  + WE;
    ushort* qb   = wto  + WE;
    ushort* kb   = qb   + XE;
    ushort* vb   = kb   + XE;
    ushort* ctxb = vb   + XE;

    cast_f32_bf16<<<(int)(XE / 4 / 256), 256, 0, stream>>>(x, xb, (int)(XE / 4));

    const dim3 gt(12, 12);
    transpose_cast_w<<<gt, 256, 0, stream>>>(Wq, wtq);
    transpose_cast_w<<<gt, 256, 0, stream>>>(Wk, wtk);
    transpose_cast_w<<<gt, 256, 0, stream>>>(Wv, wtv);
    transpose_cast_w<<<gt, 256, 0, stream>>>(Wo, wto);

    const dim3 gg(D / 64, M / 64);   // (12, 64)
    gemm_bt_bias<true ><<<gg, 256, 0, stream>>>(xb, wtq, bq, qb, M, D, D);
    gemm_bt_bias<true ><<<gg, 256, 0, stream>>>(xb, wtk, bk, kb, M, D, D);
    gemm_bt_bias<true ><<<gg, 256, 0, stream>>>(xb, wtv, bv, vb, M, D, D);

    attn_mfma<<<dim3(2048 / 64, 12, 2), 256, 0, stream>>>(qb, kb, vb, ctxb);

    gemm_bt_bias<false><<<gg, 256, 0, stream>>>(ctxb, wto, bo, (float*)d_out, M, D, D);
}

// Round 5
// 257.369 us; speedup vs baseline: 1.0776x; 1.0776x over previous
//
#include <hip/hip_runtime.h>
#include <hip/hip_bf16.h>

// ---------------------------------------------------------------------------
// B=2, S=2048, D=768, H=12, Dh=64. M = B*S = 4096.
// bf16-MFMA pipeline: cast/transpose prep -> 3 QKV GEMMs -> V relayout ->
// flash attn -> output GEMM. All matmuls v_mfma_f32_16x16x32_bf16, fp32 acc.
// R5: V transposed ONCE globally (VT[b][h][d][s]) instead of per-tile in
// attn LDS (was 16 conflicted ds_write_b16/thread/tile -> 1.65e7 bank-
// conflict cycles); K/V tiles register-prefetched across the barrier.
// ---------------------------------------------------------------------------

typedef __attribute__((ext_vector_type(8))) short short8;   // 8 x bf16 (4 VGPR)
typedef __attribute__((ext_vector_type(4))) float float4e;  // 4 x fp32 acc

// round-to-nearest-even fp32 -> bf16
__device__ __forceinline__ ushort f2bf(float f) {
    union { float f; unsigned u; } v; v.f = f;
    unsigned r = v.u + 0x7FFF + ((v.u >> 16) & 1);
    return (ushort)(r >> 16);
}

// ===========================================================================
// x [4096x768] fp32 -> bf16 (vectorized 4/thread)
// ===========================================================================
__global__ __launch_bounds__(256) void cast_f32_bf16(
    const float* __restrict__ in, ushort* __restrict__ out, int n4)
{
    int i = blockIdx.x * blockDim.x + threadIdx.x;
    if (i < n4) {
        float4 v = *(const float4*)&in[(size_t)i * 4];
        ushort4 o;
        o.x = f2bf(v.x); o.y = f2bf(v.y); o.z = f2bf(v.z); o.w = f2bf(v.w);
        *(ushort4*)&out[(size_t)i * 4] = o;
    }
}

// ===========================================================================
// W [768x768] fp32 (k-major) -> Wt [768x768] bf16 with Wt[n][k] = W[k][n].
// ===========================================================================
__global__ __launch_bounds__(256) void transpose_cast_w(
    const float* __restrict__ W, ushort* __restrict__ Wt)
{
    __shared__ float t[64][65];
    const int tid = threadIdx.x;
    const int c  = tid & 63;
    const int rg = tid >> 6;
    const int k0 = blockIdx.y * 64, n0 = blockIdx.x * 64;
    #pragma unroll
    for (int r = 0; r < 16; ++r) {
        const int row = rg * 16 + r;
        t[row][c] = W[(size_t)(k0 + row) * 768 + n0 + c];
    }
    __syncthreads();
    #pragma unroll
    for (int r = 0; r < 16; ++r) {
        const int row = rg * 16 + r;
        Wt[(size_t)(n0 + row) * 768 + k0 + c] = f2bf(t[c][row]);
    }
}

// ===========================================================================
// V [4096x768] bf16 (token-major) -> VT[b][h][d][s] bf16 (s-major per head).
// 64(token) x 64(dim) LDS tile per (s-tile, h, b); coalesced both directions.
// ===========================================================================
__global__ __launch_bounds__(256) void transpose_v(
    const ushort* __restrict__ Vb, ushort* __restrict__ VT)
{
    __shared__ ushort t[64][72];
    const int tid = threadIdx.x;
    const int b = blockIdx.z, h = blockIdx.y, s0 = blockIdx.x * 64;
    const int lr = tid >> 3;          // 0..31
    const int lc = (tid & 7) * 8;     // 0..56

    #pragma unroll
    for (int half = 0; half < 64; half += 32) {
        const int row = lr + half;    // token within tile
        *(uint4*)&t[row][lc] =
            *(const uint4*)&Vb[(size_t)(b * 2048 + s0 + row) * 768 + h * 64 + lc];
    }
    __syncthreads();
    #pragma unroll
    for (int half = 0; half < 64; half += 32) {
        const int d = lr + half;      // head-dim
        ushort tmp[8];
        #pragma unroll
        for (int i = 0; i < 8; ++i) tmp[i] = t[lc + i][d];
        *(uint4*)&VT[((size_t)(b * 12 + h) * 64 + d) * 2048 + s0 + lc] =
            *(const uint4*)tmp;
    }
}

// ===========================================================================
// GEMM: C[M,N] = A[M,K](bf16) @ Bt[N,K](bf16)^T + bias(fp32)
// 64x64 tile, BK=32, 4 waves; wave w = rows [16w,16w+16) x 64 cols (4 accs).
// ===========================================================================
template <bool OUT_BF16>
__global__ __launch_bounds__(256) void gemm_bt_bias(
    const ushort* __restrict__ A, const ushort* __restrict__ Bt,
    const float* __restrict__ bias, void* __restrict__ Cout,
    int M, int N, int K)
{
    __shared__ ushort As[64][40];
    __shared__ ushort Bs[64][40];

    const int tid  = threadIdx.x;
    const int w    = tid >> 6;
    const int lane = tid & 63;
    const int l16  = lane & 15;
    const int quad = lane >> 4;
    const int row0 = blockIdx.y * 64, col0 = blockIdx.x * 64;
    const int sr = tid >> 2, sc = (tid & 3) * 8;   // staging: 16B per thread

    float4e acc[4];
    #pragma unroll
    for (int n = 0; n < 4; ++n) acc[n] = (float4e){0.f, 0.f, 0.f, 0.f};

    for (int k0 = 0; k0 < K; k0 += 32) {
        *(uint4*)&As[sr][sc] = *(const uint4*)&A [(size_t)(row0 + sr) * K + k0 + sc];
        *(uint4*)&Bs[sr][sc] = *(const uint4*)&Bt[(size_t)(col0 + sr) * K + k0 + sc];
        __syncthreads();

        const short8 a = *(const short8*)&As[w * 16 + l16][quad * 8];
        #pragma unroll
        for (int n = 0; n < 4; ++n) {
            const short8 b = *(const short8*)&Bs[n * 16 + l16][quad * 8];
            acc[n] = __builtin_amdgcn_mfma_f32_16x16x32_bf16(a, b, acc[n], 0, 0, 0);
        }
        __syncthreads();
    }

    #pragma unroll
    for (int n = 0; n < 4; ++n) {
        const int col = col0 + n * 16 + l16;
        const float bs = bias[col];
        #pragma unroll
        for (int r = 0; r < 4; ++r) {
            const int row = row0 + w * 16 + quad * 4 + r;
            const float vv = acc[n][r] + bs;
            if (OUT_BF16) ((ushort*)Cout)[(size_t)row * N + col] = f2bf(vv);
            else          ((float*) Cout)[(size_t)row * N + col] = vv;
        }
    }
}

// ===========================================================================
// Flash attention, bf16 MFMA, NO 1/sqrt(dh) scale (matches reference).
// Block = (b, h, 64 queries); wave w owns queries [16w,16w+16).
// Q frags in registers; K staged [key][d] from Kb; V staged [d][key] from VT
// (both pure uint4 writes now); K/V tiles register-prefetched one iter ahead.
// P round-trips through LDS (C-layout -> A-layout), wave-private rows.
// ===========================================================================
__global__ __launch_bounds__(256) void attn_mfma(
    const ushort* __restrict__ Qg, const ushort* __restrict__ Kgl,
    const ushort* __restrict__ VT, ushort* __restrict__ Ctx)
{
    constexpr int S = 2048, D = 768;
    __shared__ ushort Ks [64][72];   // rows 144B: 16B-aligned, 2-way alias only
    __shared__ ushort Vts[64][72];
    __shared__ ushort Ps [64][72];

    const int tid  = threadIdx.x;
    const int w    = tid >> 6;
    const int lane = tid & 63;
    const int l16  = lane & 15;
    const int quad = lane >> 4;
    const int b = blockIdx.z, h = blockIdx.y, q0 = blockIdx.x * 64;
    const size_t hc = (size_t)h * 64;

    // Q fragments for this wave's 16 query rows (held all kernel)
    const size_t qoff = (size_t)(b * S + q0 + w * 16 + l16) * D + hc + quad * 8;
    const short8 aq0 = *(const short8*)&Qg[qoff];
    const short8 aq1 = *(const short8*)&Qg[qoff + 32];

    float mrow[4], lrow[4];
    float4e oa[4];
    #pragma unroll
    for (int r = 0; r < 4; ++r) { mrow[r] = -1e30f; lrow[r] = 0.f; }
    #pragma unroll
    for (int n = 0; n < 4; ++n) oa[n] = (float4e){0.f, 0.f, 0.f, 0.f};

    const int sr = tid >> 2;          // 0..63: key row (Ks) / head-dim (Vts)
    const int sc = (tid & 3) * 16;    // 0,16,32,48: col start (ushorts)
    const size_t vtb = ((size_t)(b * 12 + h) * 64 + sr) * 2048;  // VT row base

    // prefetch tile 0
    uint4 kA, kB, vA, vB;
    {
        const size_t gk = (size_t)(b * S + sr) * D + hc + sc;
        kA = *(const uint4*)&Kgl[gk];
        kB = *(const uint4*)&Kgl[gk + 8];
        vA = *(const uint4*)&VT[vtb + sc];
        vB = *(const uint4*)&VT[vtb + sc + 8];
    }

    for (int k0 = 0; k0 < S; k0 += 64) {
        // ---- commit prefetched tile to LDS ----
        *(uint4*)&Ks [sr][sc    ] = kA;
        *(uint4*)&Ks [sr][sc + 8] = kB;
        *(uint4*)&Vts[sr][sc    ] = vA;
        *(uint4*)&Vts[sr][sc + 8] = vB;
        __syncthreads();

        // ---- prefetch next tile (lands any time before next commit) ----
        if (k0 + 64 < S) {
            const size_t gk = (size_t)(b * S + k0 + 64 + sr) * D + hc + sc;
            kA = *(const uint4*)&Kgl[gk];
            kB = *(const uint4*)&Kgl[gk + 8];
            vA = *(const uint4*)&VT[vtb + k0 + 64 + sc];
            vB = *(const uint4*)&VT[vtb + k0 + 64 + sc + 8];
        }

        // ---- scores: S = Q K^T (chain 2 MFMAs over d) ----
        float4e sa[4];
        #pragma unroll
        for (int n = 0; n < 4; ++n) {
            const short8 b0 = *(const short8*)&Ks[n * 16 + l16][quad * 8];
            const short8 b1 = *(const short8*)&Ks[n * 16 + l16][32 + quad * 8];
            float4e z = (float4e){0.f, 0.f, 0.f, 0.f};
            z     = __builtin_amdgcn_mfma_f32_16x16x32_bf16(aq0, b0, z, 0, 0, 0);
            sa[n] = __builtin_amdgcn_mfma_f32_16x16x32_bf16(aq1, b1, z, 0, 0, 0);
        }

        // ---- online softmax (fp32), P -> LDS as bf16 ----
        #pragma unroll
        for (int r = 0; r < 4; ++r) {
            float mx = fmaxf(fmaxf(sa[0][r], sa[1][r]), fmaxf(sa[2][r], sa[3][r]));
            #pragma unroll
            for (int off = 1; off < 16; off <<= 1)
                mx = fmaxf(mx, __shfl_xor(mx, off, 64));
            const float mn = fmaxf(mrow[r], mx);
            const float alpha = __expf(mrow[r] - mn);   // first iter: 0
            const float p0 = __expf(sa[0][r] - mn);
            const float p1 = __expf(sa[1][r] - mn);
            const float p2 = __expf(sa[2][r] - mn);
            const float p3 = __expf(sa[3][r] - mn);
            float ps = p0 + p1 + p2 + p3;
            #pragma unroll
            for (int off = 1; off < 16; off <<= 1)
                ps += __shfl_xor(ps, off, 64);
            lrow[r] = lrow[r] * alpha + ps;
            mrow[r] = mn;
            const int prow = w * 16 + quad * 4 + r;
            Ps[prow][ 0 + l16] = f2bf(p0);
            Ps[prow][16 + l16] = f2bf(p1);
            Ps[prow][32 + l16] = f2bf(p2);
            Ps[prow][48 + l16] = f2bf(p3);
            oa[0][r] *= alpha; oa[1][r] *= alpha;
            oa[2][r] *= alpha; oa[3][r] *= alpha;
        }

        // ---- PV: O += P V  (Ps rows are wave-private; in-wave DS order ok) ----
        const short8 ap0 = *(const short8*)&Ps[w * 16 + l16][quad * 8];
        const short8 ap1 = *(const short8*)&Ps[w * 16 + l16][32 + quad * 8];
        #pragma unroll
        for (int n = 0; n < 4; ++n) {
            const short8 bv0 = *(const short8*)&Vts[n * 16 + l16][quad * 8];
            const short8 bv1 = *(const short8*)&Vts[n * 16 + l16][32 + quad * 8];
            oa[n] = __builtin_amdgcn_mfma_f32_16x16x32_bf16(ap0, bv0, oa[n], 0, 0, 0);
            oa[n] = __builtin_amdgcn_mfma_f32_16x16x32_bf16(ap1, bv1, oa[n], 0, 0, 0);
        }
        __syncthreads();   // protect Ks/Vts before next commit
    }

    // ---- normalize and write ctx (bf16) ----
    #pragma unroll
    for (int n = 0; n < 4; ++n) {
        #pragma unroll
        for (int r = 0; r < 4; ++r) {
            const int row = b * S + q0 + w * 16 + quad * 4 + r;
            Ctx[(size_t)row * D + hc + n * 16 + l16] = f2bf(oa[n][r] / lrow[r]);
        }
    }
}

// ===========================================================================
// Launch
// ===========================================================================
extern "C" void kernel_launch(void* const* d_in, const int* in_sizes, int n_in,
                              void* d_out, int out_size, void* d_ws, size_t ws_size,
                              hipStream_t stream)
{
    const float* x  = (const float*)d_in[0];
    const float* Wq = (const float*)d_in[1];
    const float* bq = (const float*)d_in[2];
    const float* Wk = (const float*)d_in[3];
    const float* bk = (const float*)d_in[4];
    const float* Wv = (const float*)d_in[5];
    const float* bv = (const float*)d_in[6];
    const float* Wo = (const float*)d_in[7];
    const float* bo = (const float*)d_in[8];

    const int M = 4096, D = 768;
    const size_t XE = (size_t)M * D;     // 3,145,728
    const size_t WE = (size_t)D * D;     //   589,824

    ushort* xb   = (ushort*)d_ws;        // total ws use: ~36.2 MB
    ushort* wtq  = xb   + XE;
    ushort* wtk  = wtq  + WE;
    ushort* wtv  = wtk  + WE;
    ushort* wto  = wtv  + WE;
    ushort* qb   = wto  + WE;
    ushort* kb   = qb   + XE;
    ushort* vb   = kb   + XE;
    ushort* ctxb = vb   + XE;
    ushort* vt   = xb;                   // reuse xb: dead after QKV GEMMs,
                                         // same element count (24*64*2048)

    cast_f32_bf16<<<(int)(XE / 4 / 256), 256, 0, stream>>>(x, xb, (int)(XE / 4));

    const dim3 gt(12, 12);
    transpose_cast_w<<<gt, 256, 0, stream>>>(Wq, wtq);
    transpose_cast_w<<<gt, 256, 0, stream>>>(Wk, wtk);
    transpose_cast_w<<<gt, 256, 0, stream>>>(Wv, wtv);
    transpose_cast_w<<<gt, 256, 0, stream>>>(Wo, wto);

    const dim3 gg(D / 64, M / 64);   // (12, 64)
    gemm_bt_bias<true ><<<gg, 256, 0, stream>>>(xb, wtq, bq, qb, M, D, D);
    gemm_bt_bias<true ><<<gg, 256, 0, stream>>>(xb, wtk, bk, kb, M, D, D);
    gemm_bt_bias<true ><<<gg, 256, 0, stream>>>(xb, wtv, bv, vb, M, D, D);

    transpose_v<<<dim3(32, 12, 2), 256, 0, stream>>>(vb, vt);

    attn_mfma<<<dim3(2048 / 64, 12, 2), 256, 0, stream>>>(qb, kb, vt, ctxb);

    gemm_bt_bias<false><<<gg, 256, 0, stream>>>(ctxb, wto, bo, (float*)d_out, M, D, D);
}

// Round 6
// 209.760 us; speedup vs baseline: 1.3221x; 1.2270x over previous
//
#include <hip/hip_runtime.h>
#include <hip/hip_bf16.h>

// ---------------------------------------------------------------------------
// B=2, S=2048, D=768, H=12, Dh=64. M = B*S = 4096.
// R6: (1) attention computes S^T (operand-swapped MFMA) -> softmax rows
// in-lane (2 shuffles, not 32), P stored as 4 conflict-free b64 writes,
// PV accumulates O^T from VT-frags. (2) QKV projections fused into one
// 128x128-tile GEMM over N=2304 (wtq/wtk/wtv and qb/kb/vb contiguous).
// ---------------------------------------------------------------------------

typedef __attribute__((ext_vector_type(8))) short short8;   // 8 x bf16 (4 VGPR)
typedef __attribute__((ext_vector_type(4))) float float4e;  // 4 x fp32 acc

__device__ __forceinline__ ushort f2bf(float f) {
    union { float f; unsigned u; } v; v.f = f;
    unsigned r = v.u + 0x7FFF + ((v.u >> 16) & 1);
    return (ushort)(r >> 16);
}

// ===========================================================================
// x [4096x768] fp32 -> bf16
// ===========================================================================
__global__ __launch_bounds__(256) void cast_f32_bf16(
    const float* __restrict__ in, ushort* __restrict__ out, int n4)
{
    int i = blockIdx.x * blockDim.x + threadIdx.x;
    if (i < n4) {
        float4 v = *(const float4*)&in[(size_t)i * 4];
        ushort4 o;
        o.x = f2bf(v.x); o.y = f2bf(v.y); o.z = f2bf(v.z); o.w = f2bf(v.w);
        *(ushort4*)&out[(size_t)i * 4] = o;
    }
}

// ===========================================================================
// W [768x768] fp32 -> Wt [768x768] bf16, Wt[n][k] = W[k][n].
// ===========================================================================
__global__ __launch_bounds__(256) void transpose_cast_w(
    const float* __restrict__ W, ushort* __restrict__ Wt)
{
    __shared__ float t[64][65];
    const int tid = threadIdx.x;
    const int c  = tid & 63;
    const int rg = tid >> 6;
    const int k0 = blockIdx.y * 64, n0 = blockIdx.x * 64;
    #pragma unroll
    for (int r = 0; r < 16; ++r) {
        const int row = rg * 16 + r;
        t[row][c] = W[(size_t)(k0 + row) * 768 + n0 + c];
    }
    __syncthreads();
    #pragma unroll
    for (int r = 0; r < 16; ++r) {
        const int row = rg * 16 + r;
        Wt[(size_t)(n0 + row) * 768 + k0 + c] = f2bf(t[c][row]);
    }
}

// ===========================================================================
// V [4096x768] bf16 -> VT[b][h][d][s] bf16 (s-major per head).
// ===========================================================================
__global__ __launch_bounds__(256) void transpose_v(
    const ushort* __restrict__ Vb, ushort* __restrict__ VT)
{
    __shared__ ushort t[64][72];
    const int tid = threadIdx.x;
    const int b = blockIdx.z, h = blockIdx.y, s0 = blockIdx.x * 64;
    const int lr = tid >> 3;          // 0..31
    const int lc = (tid & 7) * 8;     // 0..56

    #pragma unroll
    for (int half = 0; half < 64; half += 32) {
        const int row = lr + half;
        *(uint4*)&t[row][lc] =
            *(const uint4*)&Vb[(size_t)(b * 2048 + s0 + row) * 768 + h * 64 + lc];
    }
    __syncthreads();
    #pragma unroll
    for (int half = 0; half < 64; half += 32) {
        const int d = lr + half;
        ushort tmp[8];
        #pragma unroll
        for (int i = 0; i < 8; ++i) tmp[i] = t[lc + i][d];
        *(uint4*)&VT[((size_t)(b * 12 + h) * 64 + d) * 2048 + s0 + lc] =
            *(const uint4*)tmp;
    }
}

// ===========================================================================
// Fused QKV GEMM: Out[M,2304] = x[M,768] @ [Wq|Wk|Wv]^T + [bq|bk|bv]
// Bt rows 0..767 = Wq^T, 768..1535 = Wk^T, 1536..2303 = Wv^T (contiguous ws).
// 128x128 tile, BK=32, 4 waves in 2x2; wave = 64x64 out = 16 accs (m93
// shape). Register-prefetched staging. 128-col tiles never straddle the
// 768-boundaries (768 = 6*128), so segment select is per-block uniform.
// Output written to qb/kb/vb = Outbase + seg*M*768 (contiguous ws).
// ===========================================================================
__global__ __launch_bounds__(256) void gemm_qkv_fused(
    const ushort* __restrict__ A, const ushort* __restrict__ Bt,
    const float* __restrict__ bq, const float* __restrict__ bk,
    const float* __restrict__ bv, ushort* __restrict__ Outbase)
{
    constexpr int K = 768;
    __shared__ ushort As[128][40];
    __shared__ ushort Bs[128][40];

    const int tid  = threadIdx.x;
    const int w    = tid >> 6;
    const int lane = tid & 63;
    const int l16  = lane & 15;
    const int quad = lane >> 4;
    const int wr   = (w >> 1) * 64;   // wave row offset in tile
    const int wc   = (w & 1) * 64;    // wave col offset in tile
    const int row0 = blockIdx.y * 128, col0 = blockIdx.x * 128;
    const int sr = tid >> 2, sc = (tid & 3) * 8;

    float4e acc[4][4];
    #pragma unroll
    for (int mi = 0; mi < 4; ++mi)
        #pragma unroll
        for (int ni = 0; ni < 4; ++ni) acc[mi][ni] = (float4e){0.f,0.f,0.f,0.f};

    // prefetch k0 = 0 (2 rows per matrix per thread: sr, sr+64)
    uint4 a0 = *(const uint4*)&A [(size_t)(row0 + sr     ) * K + sc];
    uint4 a1 = *(const uint4*)&A [(size_t)(row0 + sr + 64) * K + sc];
    uint4 b0 = *(const uint4*)&Bt[(size_t)(col0 + sr     ) * K + sc];
    uint4 b1 = *(const uint4*)&Bt[(size_t)(col0 + sr + 64) * K + sc];

    for (int k0 = 0; k0 < K; k0 += 32) {
        *(uint4*)&As[sr     ][sc] = a0;
        *(uint4*)&As[sr + 64][sc] = a1;
        *(uint4*)&Bs[sr     ][sc] = b0;
        *(uint4*)&Bs[sr + 64][sc] = b1;
        __syncthreads();

        if (k0 + 32 < K) {
            const int kn = k0 + 32;
            a0 = *(const uint4*)&A [(size_t)(row0 + sr     ) * K + kn + sc];
            a1 = *(const uint4*)&A [(size_t)(row0 + sr + 64) * K + kn + sc];
            b0 = *(const uint4*)&Bt[(size_t)(col0 + sr     ) * K + kn + sc];
            b1 = *(const uint4*)&Bt[(size_t)(col0 + sr + 64) * K + kn + sc];
        }

        short8 af[4], bf[4];
        #pragma unroll
        for (int i = 0; i < 4; ++i) {
            af[i] = *(const short8*)&As[wr + i * 16 + l16][quad * 8];
            bf[i] = *(const short8*)&Bs[wc + i * 16 + l16][quad * 8];
        }
        #pragma unroll
        for (int mi = 0; mi < 4; ++mi)
            #pragma unroll
            for (int ni = 0; ni < 4; ++ni)
                acc[mi][ni] = __builtin_amdgcn_mfma_f32_16x16x32_bf16(
                    af[mi], bf[ni], acc[mi][ni], 0, 0, 0);
        __syncthreads();
    }

    // epilogue: segment select (uniform per block), bias, bf16 store
    const int seg = (col0 >= 1536) ? 2 : (col0 >= 768 ? 1 : 0);
    const float* bias = (seg == 0) ? bq : (seg == 1) ? bk : bv;
    const int ncol0 = col0 - seg * 768 + wc;
    ushort* outp = Outbase + (size_t)seg * (4096u * 768u);

    #pragma unroll
    for (int ni = 0; ni < 4; ++ni) {
        const int col = ncol0 + ni * 16 + l16;
        const float bs = bias[col];
        #pragma unroll
        for (int mi = 0; mi < 4; ++mi) {
            #pragma unroll
            for (int r = 0; r < 4; ++r) {
                const int row = row0 + wr + mi * 16 + quad * 4 + r;
                outp[(size_t)row * 768 + col] = f2bf(acc[mi][ni][r] + bs);
            }
        }
    }
}

// ===========================================================================
// GEMM (Wo only): C[M,N] = A[M,K](bf16) @ Bt[N,K]^T + bias, fp32 out.
// ===========================================================================
__global__ __launch_bounds__(256) void gemm_bt_bias_f32(
    const ushort* __restrict__ A, const ushort* __restrict__ Bt,
    const float* __restrict__ bias, float* __restrict__ Cout,
    int M, int N, int K)
{
    __shared__ ushort As[64][40];
    __shared__ ushort Bs[64][40];

    const int tid  = threadIdx.x;
    const int w    = tid >> 6;
    const int lane = tid & 63;
    const int l16  = lane & 15;
    const int quad = lane >> 4;
    const int row0 = blockIdx.y * 64, col0 = blockIdx.x * 64;
    const int sr = tid >> 2, sc = (tid & 3) * 8;

    float4e acc[4];
    #pragma unroll
    for (int n = 0; n < 4; ++n) acc[n] = (float4e){0.f, 0.f, 0.f, 0.f};

    for (int k0 = 0; k0 < K; k0 += 32) {
        *(uint4*)&As[sr][sc] = *(const uint4*)&A [(size_t)(row0 + sr) * K + k0 + sc];
        *(uint4*)&Bs[sr][sc] = *(const uint4*)&Bt[(size_t)(col0 + sr) * K + k0 + sc];
        __syncthreads();

        const short8 a = *(const short8*)&As[w * 16 + l16][quad * 8];
        #pragma unroll
        for (int n = 0; n < 4; ++n) {
            const short8 b = *(const short8*)&Bs[n * 16 + l16][quad * 8];
            acc[n] = __builtin_amdgcn_mfma_f32_16x16x32_bf16(a, b, acc[n], 0, 0, 0);
        }
        __syncthreads();
    }

    #pragma unroll
    for (int n = 0; n < 4; ++n) {
        const int col = col0 + n * 16 + l16;
        const float bs = bias[col];
        #pragma unroll
        for (int r = 0; r < 4; ++r) {
            const int row = row0 + w * 16 + quad * 4 + r;
            Cout[(size_t)row * N + col] = acc[n][r] + bs;
        }
    }
}

// ===========================================================================
// Flash attention, S^T formulation. Block = (b, h, 64 queries); wave w owns
// queries [16w,16w+16). mfma(X,Y,C): D[m][n]=sum_k X[m][k]Y[n][k],
// D layout col=lane&15=n, row=quad*4+r=m (measured).
//   scores:  D[key][query]  = mfma(K-frag, Q-frag)  -> lane: query=l16,
//            keys kb*16+quad*4+r. Softmax row = in-lane 16 + shfl_xor(16,32).
//   P store: 4 contiguous keys/lane -> 4x ds_write_b64, conflict-free.
//   PV:      D[d][query]    = mfma(VT-frag, P-frag) -> O^T accumulate.
//   epilogue: 4 contiguous d per (db) -> ushort4 global stores.
// Ps rows are wave-private; in-wave DS write->read order (validated R4/R5).
// ===========================================================================
__global__ __launch_bounds__(256) void attn_mfma(
    const ushort* __restrict__ Qg, const ushort* __restrict__ Kgl,
    const ushort* __restrict__ VT, ushort* __restrict__ Ctx)
{
    constexpr int S = 2048, D = 768;
    __shared__ ushort Ks [64][72];   // [key][d]
    __shared__ ushort Vts[64][72];   // [d][key]
    __shared__ ushort Ps [64][72];   // [w*16+query][key]

    const int tid  = threadIdx.x;
    const int w    = tid >> 6;
    const int lane = tid & 63;
    const int l16  = lane & 15;
    const int quad = lane >> 4;
    const int b = blockIdx.z, h = blockIdx.y, q0 = blockIdx.x * 64;
    const size_t hc = (size_t)h * 64;

    // Q frags (Y operand of score mfma): lane holds Q[q0+w*16+l16][quad*8+j]
    const size_t qoff = (size_t)(b * S + q0 + w * 16 + l16) * D + hc + quad * 8;
    const short8 yq0 = *(const short8*)&Qg[qoff];
    const short8 yq1 = *(const short8*)&Qg[qoff + 32];

    float m_ = -1e30f, l_ = 0.f;
    float4e oa[4];
    #pragma unroll
    for (int n = 0; n < 4; ++n) oa[n] = (float4e){0.f, 0.f, 0.f, 0.f};

    const int sr = tid >> 2;          // key row (Ks) / head-dim (Vts)
    const int sc = (tid & 3) * 16;
    const size_t vtb = ((size_t)(b * 12 + h) * 64 + sr) * 2048;

    uint4 kA, kB, vA, vB;
    {
        const size_t gk = (size_t)(b * S + sr) * D + hc + sc;
        kA = *(const uint4*)&Kgl[gk];
        kB = *(const uint4*)&Kgl[gk + 8];
        vA = *(const uint4*)&VT[vtb + sc];
        vB = *(const uint4*)&VT[vtb + sc + 8];
    }

    for (int k0 = 0; k0 < S; k0 += 64) {
        *(uint4*)&Ks [sr][sc    ] = kA;
        *(uint4*)&Ks [sr][sc + 8] = kB;
        *(uint4*)&Vts[sr][sc    ] = vA;
        *(uint4*)&Vts[sr][sc + 8] = vB;
        __syncthreads();

        if (k0 + 64 < S) {
            const size_t gk = (size_t)(b * S + k0 + 64 + sr) * D + hc + sc;
            kA = *(const uint4*)&Kgl[gk];
            kB = *(const uint4*)&Kgl[gk + 8];
            vA = *(const uint4*)&VT[vtb + k0 + 64 + sc];
            vB = *(const uint4*)&VT[vtb + k0 + 64 + sc + 8];
        }

        // ---- S^T: lane gets S[query=l16][key=kb*16+quad*4+r] ----
        float4e sa[4];
        #pragma unroll
        for (int kb = 0; kb < 4; ++kb) {
            const short8 xk0 = *(const short8*)&Ks[kb * 16 + l16][quad * 8];
            const short8 xk1 = *(const short8*)&Ks[kb * 16 + l16][32 + quad * 8];
            float4e z = (float4e){0.f, 0.f, 0.f, 0.f};
            z      = __builtin_amdgcn_mfma_f32_16x16x32_bf16(xk0, yq0, z, 0, 0, 0);
            sa[kb] = __builtin_amdgcn_mfma_f32_16x16x32_bf16(xk1, yq1, z, 0, 0, 0);
        }

        // ---- online softmax: 16 vals in-lane + 2 cross-quad shuffles ----
        float mx = -1e30f;
        #pragma unroll
        for (int kb = 0; kb < 4; ++kb)
            #pragma unroll
            for (int r = 0; r < 4; ++r) mx = fmaxf(mx, sa[kb][r]);
        mx = fmaxf(mx, __shfl_xor(mx, 16, 64));
        mx = fmaxf(mx, __shfl_xor(mx, 32, 64));
        const float mn = fmaxf(m_, mx);
        const float alpha = __expf(m_ - mn);    // first iter: 0
        float p[4][4], ps = 0.f;
        #pragma unroll
        for (int kb = 0; kb < 4; ++kb)
            #pragma unroll
            for (int r = 0; r < 4; ++r) {
                p[kb][r] = __expf(sa[kb][r] - mn);
                ps += p[kb][r];
            }
        ps += __shfl_xor(ps, 16, 64);
        ps += __shfl_xor(ps, 32, 64);
        l_ = l_ * alpha + ps;
        m_ = mn;

        // ---- P -> LDS: 4 contiguous keys per b64 write, conflict-free ----
        #pragma unroll
        for (int kb = 0; kb < 4; ++kb) {
            ushort4 pk;
            pk.x = f2bf(p[kb][0]); pk.y = f2bf(p[kb][1]);
            pk.z = f2bf(p[kb][2]); pk.w = f2bf(p[kb][3]);
            *(ushort4*)&Ps[w * 16 + l16][kb * 16 + quad * 4] = pk;
        }

        // ---- rescale O^T and accumulate PV ----
        #pragma unroll
        for (int n = 0; n < 4; ++n)
            #pragma unroll
            for (int r = 0; r < 4; ++r) oa[n][r] *= alpha;

        const short8 yp0 = *(const short8*)&Ps[w * 16 + l16][quad * 8];
        const short8 yp1 = *(const short8*)&Ps[w * 16 + l16][32 + quad * 8];
        #pragma unroll
        for (int db = 0; db < 4; ++db) {
            const short8 xv0 = *(const short8*)&Vts[db * 16 + l16][quad * 8];
            const short8 xv1 = *(const short8*)&Vts[db * 16 + l16][32 + quad * 8];
            oa[db] = __builtin_amdgcn_mfma_f32_16x16x32_bf16(xv0, yp0, oa[db], 0, 0, 0);
            oa[db] = __builtin_amdgcn_mfma_f32_16x16x32_bf16(xv1, yp1, oa[db], 0, 0, 0);
        }
        __syncthreads();
    }

    // ---- normalize, write ctx: lane owns query l16, dims db*16+quad*4+r ----
    const float inv = 1.0f / l_;
    const size_t crow = (size_t)(b * S + q0 + w * 16 + l16) * D + hc;
    #pragma unroll
    for (int db = 0; db < 4; ++db) {
        ushort4 ov;
        ov.x = f2bf(oa[db][0] * inv); ov.y = f2bf(oa[db][1] * inv);
        ov.z = f2bf(oa[db][2] * inv); ov.w = f2bf(oa[db][3] * inv);
        *(ushort4*)&Ctx[crow + db * 16 + quad * 4] = ov;
    }
}

// ===========================================================================
// Launch
// ===========================================================================
extern "C" void kernel_launch(void* const* d_in, const int* in_sizes, int n_in,
                              void* d_out, int out_size, void* d_ws, size_t ws_size,
                              hipStream_t stream)
{
    const float* x  = (const float*)d_in[0];
    const float* Wq = (const float*)d_in[1];
    const float* bq = (const float*)d_in[2];
    const float* Wk = (const float*)d_in[3];
    const float* bk = (const float*)d_in[4];
    const float* Wv = (const float*)d_in[5];
    const float* bv = (const float*)d_in[6];
    const float* Wo = (const float*)d_in[7];
    const float* bo = (const float*)d_in[8];

    const int M = 4096, D = 768;
    const size_t XE = (size_t)M * D;     // 3,145,728
    const size_t WE = (size_t)D * D;     //   589,824

    ushort* xb   = (ushort*)d_ws;
    ushort* wtq  = xb   + XE;            // wtq/wtk/wtv contiguous = fused Bt
    ushort* wtk  = wtq  + WE;
    ushort* wtv  = wtk  + WE;
    ushort* wto  = wtv  + WE;
    ushort* qb   = wto  + WE;            // qb/kb/vb contiguous = fused out
    ushort* kb   = qb   + XE;
    ushort* vb   = kb   + XE;
    ushort* ctxb = vb   + XE;
    ushort* vt   = xb;                   // reuse xb (dead after fused GEMM)

    cast_f32_bf16<<<(int)(XE / 4 / 256), 256, 0, stream>>>(x, xb, (int)(XE / 4));

    const dim3 gt(12, 12);
    transpose_cast_w<<<gt, 256, 0, stream>>>(Wq, wtq);
    transpose_cast_w<<<gt, 256, 0, stream>>>(Wk, wtk);
    transpose_cast_w<<<gt, 256, 0, stream>>>(Wv, wtv);
    transpose_cast_w<<<gt, 256, 0, stream>>>(Wo, wto);

    gemm_qkv_fused<<<dim3(2304 / 128, 4096 / 128), 256, 0, stream>>>(
        xb, wtq, bq, bk, bv, qb);

    transpose_v<<<dim3(32, 12, 2), 256, 0, stream>>>(vb, vt);

    attn_mfma<<<dim3(2048 / 64, 12, 2), 256, 0, stream>>>(qb, kb, vt, ctxb);

    gemm_bt_bias_f32<<<dim3(D / 64, M / 64), 256, 0, stream>>>(
        ctxb, wto, bo, (float*)d_out, M, D, D);
}